// Round 3
// baseline (6617.782 us; speedup 1.0000x reference)
//
#include <hip/hip_runtime.h>
#include <hip/hip_bf16.h>

typedef __hip_bfloat16 bf16;

#define BB   64
#define CC   3
#define TLEN 256
#define VJ   21
#define DM   128
#define NH   4
#define DH   32
#define KT   9
#define NFR  (BB*TLEN)
#define TCT  32
#define NIN  22

__device__ __forceinline__ float b2f(bf16 x){ return __bfloat162float(x); }
__device__ __forceinline__ bf16  f2b(float x){ return __float2bfloat16(x); }

// ---------------- input dtype detection: bf16-interpret x, look for huge/NaN ----------------
__global__ void detect_dtype(const void* __restrict__ xin, int nus, int* __restrict__ flag){
  const unsigned short* u = (const unsigned short*)xin;
  int lim = nus < 65536 ? nus : 65536;
  int bad = 0;
  for (int k = threadIdx.x; k < lim; k += 256){
    float f = __uint_as_float(((unsigned)u[k]) << 16);
    if (!(fabsf(f) < 1e6f)) bad = 1;   // catches huge, Inf, NaN
  }
  if (bad) atomicOr(flag, 1);          // flag!=0  =>  inputs are float32
}

struct ConvArgs { const void* src[NIN]; int off[NIN+1]; };

// ---------------- normalize all inputs to canonical bf16 copies in ws ----------------
__global__ void convert_inputs(ConvArgs a, bf16* __restrict__ dst,
                               const int* __restrict__ flag, int total){
  int i = blockIdx.x*256 + threadIdx.x;
  if (i >= total) return;
  bool isf32 = (*flag != 0);
  int k = 0;
  while (i >= a.off[k+1]) ++k;
  int j = i - a.off[k];
  float v;
  if (isf32) v = ((const float*)a.src[k])[j];
  else       v = __uint_as_float(((unsigned)((const unsigned short*)a.src[k])[j]) << 16);
  dst[i] = f2b(v);
}

// ---------------- weight transposes: gw[d][c]->gwt[c][d], tw[d][c][k]->twt[c][k][d] ----------------
__global__ void prep_weights(const bf16* __restrict__ gw1, const bf16* __restrict__ gw2,
                             const bf16* __restrict__ tw1, const bf16* __restrict__ tw2,
                             bf16* __restrict__ gwt1, bf16* __restrict__ gwt2,
                             bf16* __restrict__ twt1, bf16* __restrict__ twt2){
  int i = blockIdx.x*256 + threadIdx.x;
  if (i < DM*DM){
    int c = i / DM, d = i % DM;
    gwt1[i] = gw1[d*DM + c];
    gwt2[i] = gw2[d*DM + c];
  }
  if (i < DM*DM*KT){
    int d = i % DM; int k = (i/DM) % KT; int c = i/(DM*KT);
    twt1[i] = tw1[(d*DM + c)*KT + k];
    twt2[i] = tw2[(d*DM + c)*KT + k];
  }
}

// ---------------- attention: one block per frame n = b*T + t ----------------
__global__ __launch_bounds__(256) void attn_kernel(
    const bf16* __restrict__ x,  const bf16* __restrict__ cw, const bf16* __restrict__ cb,
    const bf16* __restrict__ je, const bf16* __restrict__ gbias,
    const bf16* __restrict__ wq, const bf16* __restrict__ bq,
    const bf16* __restrict__ wk, const bf16* __restrict__ bk,
    const bf16* __restrict__ wv, const bf16* __restrict__ bv,
    const bf16* __restrict__ wo, const bf16* __restrict__ bo,
    float* __restrict__ attn_out, bf16* __restrict__ feat_out)
{
  const int n = blockIdx.x;
  const int b = n / TLEN, t = n % TLEN;
  const int tid = threadIdx.x;
  __shared__ float sf[VJ][132];   // feat, later reused as attention-output (ao)
  __shared__ float sq[VJ][132];
  __shared__ float sk[VJ][132];
  __shared__ float sv[VJ][132];
  __shared__ float sc[NH*VJ*VJ];  // scores -> probabilities (in place)
  __shared__ float rmax[NH*VJ], rinv[NH*VJ];

  // feat[v][d] = coords@cw + cb + joint_emb
  for (int idx = tid; idx < VJ*DM; idx += 256){
    int d = idx & (DM-1), v = idx >> 7;
    float acc = b2f(cb[d]) + b2f(je[v*DM + d]);
    #pragma unroll
    for (int c = 0; c < CC; ++c)
      acc = fmaf(b2f(x[((size_t)(b*CC + c)*TLEN + t)*VJ + v]), b2f(cw[c*DM + d]), acc);
    sf[v][d] = acc;
  }
  __syncthreads();
  // q,k,v projections (share feat read)
  for (int idx = tid; idx < VJ*DM; idx += 256){
    int d = idx & (DM-1), v = idx >> 7;
    float aq = b2f(bq[d]), ak = b2f(bk[d]), av = b2f(bv[d]);
    for (int e = 0; e < DM; ++e){
      float f = sf[v][e];
      aq = fmaf(f, b2f(wq[e*DM + d]), aq);
      ak = fmaf(f, b2f(wk[e*DM + d]), ak);
      av = fmaf(f, b2f(wv[e*DM + d]), av);
    }
    sq[v][d] = aq; sk[v][d] = ak; sv[v][d] = av;
  }
  __syncthreads();
  // scores[h][i][j] = scale*q.k + graph_bias
  const float scale = 0.17677669529663687f;  // 1/sqrt(32)
  for (int idx = tid; idx < NH*VJ*VJ; idx += 256){
    int j = idx % VJ, i2 = (idx/VJ) % VJ, h = idx/(VJ*VJ);
    float a = 0.f;
    #pragma unroll
    for (int dd = 0; dd < DH; ++dd)
      a = fmaf(sq[i2][h*DH + dd], sk[j][h*DH + dd], a);
    sc[idx] = a*scale + b2f(gbias[i2*VJ + j]);
  }
  __syncthreads();
  // softmax row stats (84 rows)
  for (int r = tid; r < NH*VJ; r += 256){
    float m = -1e30f;
    for (int j = 0; j < VJ; ++j) m = fmaxf(m, sc[r*VJ + j]);
    float s = 0.f;
    for (int j = 0; j < VJ; ++j) s += __expf(sc[r*VJ + j] - m);
    rmax[r] = m; rinv[r] = 1.0f/s;
  }
  __syncthreads();
  // normalize + write attn output (f32, coalesced, contiguous per frame)
  for (int idx = tid; idx < NH*VJ*VJ; idx += 256){
    int r = idx / VJ;
    float e = __expf(sc[idx] - rmax[r]) * rinv[r];
    sc[idx] = e;
    attn_out[(size_t)n*(NH*VJ*VJ) + idx] = e;
  }
  __syncthreads();
  // ao[v][d] = sum_j attn[h(d)][v][j] * val[j][d]   (reuse sf)
  for (int idx = tid; idx < VJ*DM; idx += 256){
    int d = idx & (DM-1), v = idx >> 7, h = d >> 5;
    float acc = 0.f;
    #pragma unroll
    for (int j = 0; j < VJ; ++j)
      acc = fmaf(sc[(h*VJ + v)*VJ + j], sv[j][d], acc);
    sf[v][d] = acc;
  }
  __syncthreads();
  // out projection, write feat [B,T,V,D] bf16 (coalesced in d)
  for (int idx = tid; idx < VJ*DM; idx += 256){
    int d = idx & (DM-1), v = idx >> 7;
    float acc = b2f(bo[d]);
    for (int e = 0; e < DM; ++e)
      acc = fmaf(sf[v][e], b2f(wo[e*DM + d]), acc);
    feat_out[((size_t)n*VJ + v)*DM + d] = f2b(acc);
  }
}

// ---------------- GCN: spatial aggregation + 1x1 conv + relu; one block per frame ----------------
__global__ __launch_bounds__(256) void gcn_kernel(const bf16* __restrict__ fin,
                                                  const bf16* __restrict__ An,
                                                  const bf16* __restrict__ gwt,  // [c][d]
                                                  const bf16* __restrict__ gb,
                                                  bf16* __restrict__ yout){
  const int n = blockIdx.x;
  const int tid = threadIdx.x;
  __shared__ float sx[VJ][132];
  __shared__ float sa[VJ][132];
  __shared__ float sA[VJ*VJ];
  for (int i = tid; i < VJ*VJ; i += 256) sA[i] = b2f(An[i]);
  for (int idx = tid; idx < VJ*DM; idx += 256){
    int d = idx & (DM-1), v = idx >> 7;
    sx[v][d] = b2f(fin[((size_t)n*VJ + v)*DM + d]);
  }
  __syncthreads();
  // agg[w][c] = sum_u A[u][w] * x[u][c]
  for (int idx = tid; idx < VJ*DM; idx += 256){
    int c = idx & (DM-1), w = idx >> 7;
    float acc = 0.f;
    #pragma unroll
    for (int u = 0; u < VJ; ++u)
      acc = fmaf(sA[u*VJ + w], sx[u][c], acc);
    sa[w][c] = acc;
  }
  __syncthreads();
  // y[v][d] = relu(gw @ agg + gb)
  for (int idx = tid; idx < VJ*DM; idx += 256){
    int d = idx & (DM-1), v = idx >> 7;
    float acc = b2f(gb[d]);
    for (int c = 0; c < DM; ++c)
      acc = fmaf(sa[v][c], b2f(gwt[c*DM + d]), acc);
    yout[((size_t)n*VJ + v)*DM + d] = f2b(fmaxf(acc, 0.f));
  }
}

// ---------------- temporal conv (KT=9) + bias + residual + relu ----------------
template<int TP>
__device__ __forceinline__ void tconv_core(const float* sy, const bf16* __restrict__ twt,
                                           int d, float* acc){
  for (int c = 0; c < DM; ++c){
    float4 y4[10];
    const float4* row = reinterpret_cast<const float4*>(sy + c*44);
    #pragma unroll
    for (int q = 0; q < 10; ++q) y4[q] = row[q];
    const float* yr = reinterpret_cast<const float*>(y4);
    float wreg[KT];
    #pragma unroll
    for (int k = 0; k < KT; ++k) wreg[k] = b2f(twt[(c*KT + k)*DM + d]);
    #pragma unroll
    for (int i = 0; i < 16; ++i){
      #pragma unroll
      for (int k = 0; k < KT; ++k)
        acc[i] = fmaf(wreg[k], yr[TP + 2*i + k], acc[i]);  // all indices compile-time
    }
  }
}

__global__ __launch_bounds__(256) void tconv_kernel(const bf16* __restrict__ y1,
                                                    const bf16* res,         // may alias outp (in-place)
                                                    const bf16* __restrict__ twt,  // [c][k][d]
                                                    const bf16* __restrict__ tb,
                                                    bf16* outp){
  const int bid = blockIdx.x;
  const int b   = bid / (VJ*(TLEN/TCT));
  const int rem = bid % (VJ*(TLEN/TCT));
  const int v   = rem / (TLEN/TCT);
  const int t0  = (rem % (TLEN/TCT)) * TCT;
  const int tid = threadIdx.x;
  __shared__ __align__(16) float sy[DM][44];  // 40 t-values (t0-4 .. t0+35), 16B-aligned rows
  for (int li = tid; li < 40*DM; li += 256){
    int c = li & (DM-1); int j = li >> 7;
    int t = t0 + j - 4;
    float val = 0.f;
    if (t >= 0 && t < TLEN) val = b2f(y1[((size_t)(b*TLEN + t)*VJ + v)*DM + c]);
    sy[c][j] = val;
  }
  __syncthreads();
  const int d  = tid & (DM-1);
  const int tp = tid >> 7;          // 0 or 1; thread owns t = t0 + tp + 2*i
  float acc[16];
  float tbv = b2f(tb[d]);
  #pragma unroll
  for (int i = 0; i < 16; ++i) acc[i] = tbv;
  if (tp == 0) tconv_core<0>(&sy[0][0], twt, d, acc);
  else         tconv_core<1>(&sy[0][0], twt, d, acc);
  #pragma unroll
  for (int i = 0; i < 16; ++i){
    int t = t0 + tp + 2*i;
    size_t idx = ((size_t)(b*TLEN + t)*VJ + v)*DM + d;
    float r = b2f(res[idx]);      // same idx this thread writes -> in-place safe
    outp[idx] = f2b(fmaxf(acc[i] + r, 0.f));
  }
}

// ---------------- [B,T,V,D] bf16 -> [B,D,T,V] f32 transpose into d_out ----------------
__global__ __launch_bounds__(256) void transpose_out(const bf16* __restrict__ fin,
                                                     float* __restrict__ fout){
  const int bid = blockIdx.x;
  const int b   = bid >> 5;
  const int rem = bid & 31;
  const int t0  = (rem >> 2) * 32;
  const int d0  = (rem & 3) * 32;
  __shared__ bf16 tile[32][VJ][33];
  const int tid = threadIdx.x;
  for (int idx = tid; idx < 32*VJ*32; idx += 256){
    int dl = idx & 31;
    int v  = (idx >> 5) % VJ;
    int tl = idx / (32*VJ);
    tile[tl][v][dl] = fin[((size_t)(b*TLEN + t0 + tl)*VJ + v)*DM + d0 + dl];
  }
  __syncthreads();
  for (int idx = tid; idx < 32*VJ*32; idx += 256){
    int j  = idx % (32*VJ);
    int dl = idx / (32*VJ);
    int tl = j / VJ, v = j % VJ;
    fout[((size_t)(b*DM + d0 + dl)*TLEN + t0 + tl)*VJ + v] = b2f(tile[tl][v][dl]);
  }
}

extern "C" void kernel_launch(void* const* d_in, const int* in_sizes, int n_in,
                              void* d_out, int out_size, void* d_ws, size_t ws_size,
                              hipStream_t stream){
  float* outf = (float*)d_out;                     // [B,D,T,V] f32
  const size_t featElems = (size_t)NFR*VJ*DM;      // 44,040,192
  float* outa = outf + featElems;                  // [N,H,V,V] f32

  // ---- workspace layout ----
  int*  flag = (int*)d_ws;                         // 16B slot
  bf16* cin  = (bf16*)((char*)d_ws + 16);          // canonical bf16 inputs
  ConvArgs ca;
  int total = 0;
  for (int i = 0; i < NIN; ++i){
    ca.src[i] = d_in[i];
    ca.off[i] = total;
    total += in_sizes[i];
  }
  ca.off[NIN] = total;

  bf16* buf0 = cin + ((total + 15) & ~15);         // running feature map [B,T,V,D]
  bf16* buf1 = buf0 + featElems;                   // gcn output scratch
  bf16* gwt1 = buf1 + featElems;
  bf16* gwt2 = gwt1 + DM*DM;
  bf16* twt1 = gwt2 + DM*DM;
  bf16* twt2 = twt1 + DM*DM*KT;
  size_t needed = (size_t)((char*)(twt2 + DM*DM*KT) - (char*)d_ws);
  if (ws_size < needed) return;   // loud correctness failure instead of corruption

  const bf16* x    = cin + ca.off[0];
  const bf16* cw   = cin + ca.off[1];
  const bf16* cb   = cin + ca.off[2];
  const bf16* je   = cin + ca.off[3];
  const bf16* gbias= cin + ca.off[4];
  const bf16* wq   = cin + ca.off[5];
  const bf16* bq   = cin + ca.off[6];
  const bf16* wk   = cin + ca.off[7];
  const bf16* bk   = cin + ca.off[8];
  const bf16* wv   = cin + ca.off[9];
  const bf16* bv   = cin + ca.off[10];
  const bf16* wo   = cin + ca.off[11];
  const bf16* bo   = cin + ca.off[12];
  const bf16* gw1  = cin + ca.off[13];
  const bf16* gb1  = cin + ca.off[14];
  const bf16* tw1  = cin + ca.off[15];
  const bf16* tb1  = cin + ca.off[16];
  const bf16* gw2  = cin + ca.off[17];
  const bf16* gb2  = cin + ca.off[18];
  const bf16* tw2  = cin + ca.off[19];
  const bf16* tb2  = cin + ca.off[20];
  const bf16* An   = cin + ca.off[21];

  hipMemsetAsync(flag, 0, sizeof(int), stream);
  detect_dtype<<<1, 256, 0, stream>>>(d_in[0], in_sizes[0], flag);
  convert_inputs<<<(total + 255)/256, 256, 0, stream>>>(ca, cin, flag, total);
  prep_weights<<<(DM*DM*KT + 255)/256, 256, 0, stream>>>(gw1, gw2, tw1, tw2,
                                                         gwt1, gwt2, twt1, twt2);
  attn_kernel<<<NFR, 256, 0, stream>>>(x, cw, cb, je, gbias, wq, bq, wk, bk,
                                       wv, bv, wo, bo, outa, buf0);
  gcn_kernel<<<NFR, 256, 0, stream>>>(buf0, An, gwt1, gb1, buf1);
  tconv_kernel<<<BB*VJ*(TLEN/TCT), 256, 0, stream>>>(buf1, buf0, twt1, tb1, buf0);
  gcn_kernel<<<NFR, 256, 0, stream>>>(buf0, An, gwt2, gb2, buf1);
  tconv_kernel<<<BB*VJ*(TLEN/TCT), 256, 0, stream>>>(buf1, buf0, twt2, tb2, buf0);
  transpose_out<<<BB*(TLEN/32)*(DM/32), 256, 0, stream>>>(buf0, outf);
}

// Round 4
// 3365.240 us; speedup vs baseline: 1.9665x; 1.9665x over previous
//
#include <hip/hip_runtime.h>
#include <hip/hip_bf16.h>

typedef __hip_bfloat16 bf16;
typedef __attribute__((ext_vector_type(8))) short short8v;
typedef __attribute__((ext_vector_type(4))) float float4v;

#define BB   64
#define CC   3
#define TLEN 256
#define VJ   21
#define DM   128
#define NH   4
#define DH   32
#define KT   9
#define NFR  (BB*TLEN)
#define MTOK (NFR*VJ)          // 344064 tokens, = 5376 * 64
#define NIN  22

__device__ __forceinline__ float b2f(bf16 x){ return __bfloat162float(x); }
__device__ __forceinline__ bf16  f2b(float x){ return __float2bfloat16(x); }
__device__ __forceinline__ float hb2f(short s){ return __uint_as_float(((unsigned)(unsigned short)s) << 16); }

// ---------------- input dtype detection ----------------
__global__ void detect_dtype(const void* __restrict__ xin, int nus, int* __restrict__ flag){
  const unsigned short* u = (const unsigned short*)xin;
  int lim = nus < 65536 ? nus : 65536;
  int bad = 0;
  for (int k = threadIdx.x; k < lim; k += 256){
    float f = __uint_as_float(((unsigned)u[k]) << 16);
    if (!(fabsf(f) < 1e6f)) bad = 1;
  }
  if (bad) atomicOr(flag, 1);          // flag!=0 => inputs are float32
}

struct ConvArgs { const void* src[NIN]; int off[NIN+1]; };

__global__ void convert_inputs(ConvArgs a, bf16* __restrict__ dst,
                               const int* __restrict__ flag, int total){
  int i = blockIdx.x*256 + threadIdx.x;
  if (i >= total) return;
  bool isf32 = (*flag != 0);
  int k = 0;
  while (i >= a.off[k+1]) ++k;
  int j = i - a.off[k];
  float v;
  if (isf32) v = ((const float*)a.src[k])[j];
  else       v = __uint_as_float(((unsigned)((const unsigned short*)a.src[k])[j]) << 16);
  dst[i] = f2b(v);
}

// ---------------- weight prep: wqT/wkT/wvT/woT [n][k] = w[k][n]; twT[tap][d][c] ----------------
__global__ void prep_weights(const bf16* __restrict__ wq, const bf16* __restrict__ wk,
                             const bf16* __restrict__ wv, const bf16* __restrict__ wo,
                             const bf16* __restrict__ tw1, const bf16* __restrict__ tw2,
                             bf16* __restrict__ wqT, bf16* __restrict__ wkT,
                             bf16* __restrict__ wvT, bf16* __restrict__ woT,
                             bf16* __restrict__ twT1, bf16* __restrict__ twT2){
  int i = blockIdx.x*256 + threadIdx.x;
  if (i < DM*DM){
    int d = i >> 7, e = i & 127;            // wT[d][e] = w[e][d]
    wqT[i] = wq[e*DM + d];
    wkT[i] = wk[e*DM + d];
    wvT[i] = wv[e*DM + d];
    woT[i] = wo[e*DM + d];
  }
  if (i < KT*DM*DM){
    int c = i & 127; int d = (i >> 7) & 127; int tap = i >> 14;
    twT1[i] = tw1[(d*DM + c)*KT + tap];     // tw [d][c][kt][1]
    twT2[i] = tw2[(d*DM + c)*KT + tap];
  }
}

// ---------------- encode: feat[n][d] = coords@cw + cb + je ----------------
__global__ __launch_bounds__(256) void encode_kernel(const bf16* __restrict__ x,
                                                     const bf16* __restrict__ cw,
                                                     const bf16* __restrict__ cb,
                                                     const bf16* __restrict__ je,
                                                     bf16* __restrict__ feat){
  int idx = blockIdx.x*256 + threadIdx.x;        // one per (token, 8-wide d group)
  if (idx >= MTOK*16) return;
  int d0 = (idx & 15) * 8;
  int n  = idx >> 4;
  int v  = n % VJ; int t = (n / VJ) % TLEN; int b = n / (VJ*TLEN);
  float xs[CC];
  #pragma unroll
  for (int c = 0; c < CC; ++c)
    xs[c] = b2f(x[((size_t)(b*CC + c)*TLEN + t)*VJ + v]);
  short8v cwv[CC];
  #pragma unroll
  for (int c = 0; c < CC; ++c)
    cwv[c] = *reinterpret_cast<const short8v*>(cw + c*DM + d0);
  short8v cbv = *reinterpret_cast<const short8v*>(cb + d0);
  short8v jev = *reinterpret_cast<const short8v*>(je + v*DM + d0);
  #pragma unroll
  for (int e = 0; e < 8; ++e){
    float acc = hb2f(cbv[e]) + hb2f(jev[e]);
    #pragma unroll
    for (int c = 0; c < CC; ++c) acc = fmaf(xs[c], hb2f(cwv[c][e]), acc);
    feat[(size_t)n*DM + d0 + e] = f2b(acc);
  }
}

// ---------------- MFMA GEMM: C[M,128] = A[M,128] @ W, W given as Bt[n][k]; +bias, opt relu ----------------
template<bool RELU>
__global__ __launch_bounds__(256) void gemm128(const bf16* __restrict__ A,
                                               const bf16* __restrict__ Bt,
                                               const bf16* __restrict__ bias,
                                               bf16* __restrict__ Cout){
  const int wave = threadIdx.x >> 6;
  const int lane = threadIdx.x & 63;
  const int r0   = blockIdx.x*64 + wave*16;
  const int arow = r0 + (lane & 15);
  const int koff = (lane >> 4) * 8;
  float4v acc[8];
  #pragma unroll
  for (int nt = 0; nt < 8; ++nt) acc[nt] = (float4v){0.f,0.f,0.f,0.f};
  #pragma unroll
  for (int ks = 0; ks < 4; ++ks){
    short8v a = *reinterpret_cast<const short8v*>(A + (size_t)arow*DM + ks*32 + koff);
    #pragma unroll
    for (int nt = 0; nt < 8; ++nt){
      short8v b = *reinterpret_cast<const short8v*>(Bt + (nt*16 + (lane & 15))*DM + ks*32 + koff);
      acc[nt] = __builtin_amdgcn_mfma_f32_16x16x32_bf16(a, b, acc[nt], 0, 0, 0);
    }
  }
  const int crow0 = r0 + (lane >> 4)*4;
  #pragma unroll
  for (int nt = 0; nt < 8; ++nt){
    int col = nt*16 + (lane & 15);
    float bv = b2f(bias[col]);
    #pragma unroll
    for (int j = 0; j < 4; ++j){
      float val = acc[nt][j] + bv;
      if (RELU) val = fmaxf(val, 0.f);
      Cout[(size_t)(crow0 + j)*DM + col] = f2b(val);
    }
  }
}

// ---------------- temporal conv as 9-tap shifted GEMM + bias + residual + relu ----------------
__global__ __launch_bounds__(256) void tconv_gemm(const bf16* __restrict__ Y,     // [M][128]
                                                  const bf16* __restrict__ twT,   // [9][128][128]
                                                  const bf16* __restrict__ bias,
                                                  const bf16* __restrict__ resid, // may alias Cout
                                                  bf16* Cout){
  const int wave = threadIdx.x >> 6;
  const int lane = threadIdx.x & 63;
  const int r0   = blockIdx.x*64 + wave*16;
  const int arow = r0 + (lane & 15);
  const int trow = (arow / VJ) % TLEN;
  const int koff = (lane >> 4) * 8;
  float4v acc[8];
  #pragma unroll
  for (int nt = 0; nt < 8; ++nt) acc[nt] = (float4v){0.f,0.f,0.f,0.f};
  for (int tap = 0; tap < KT; ++tap){
    const int ts = trow + tap - 4;
    const bool valid = (ts >= 0) && (ts < TLEN);
    const bf16* Arow = Y + ((long)arow + (long)(tap - 4)*VJ)*DM;
    const bf16* Btap = twT + tap*DM*DM;
    #pragma unroll
    for (int ks = 0; ks < 4; ++ks){
      short8v a = {0,0,0,0,0,0,0,0};
      if (valid) a = *reinterpret_cast<const short8v*>(Arow + ks*32 + koff);
      #pragma unroll
      for (int nt = 0; nt < 8; ++nt){
        short8v b = *reinterpret_cast<const short8v*>(Btap + (nt*16 + (lane & 15))*DM + ks*32 + koff);
        acc[nt] = __builtin_amdgcn_mfma_f32_16x16x32_bf16(a, b, acc[nt], 0, 0, 0);
      }
    }
  }
  const int crow0 = r0 + (lane >> 4)*4;
  #pragma unroll
  for (int nt = 0; nt < 8; ++nt){
    int col = nt*16 + (lane & 15);
    float bv = b2f(bias[col]);
    #pragma unroll
    for (int j = 0; j < 4; ++j){
      size_t idx = (size_t)(crow0 + j)*DM + col;
      float val = acc[nt][j] + bv + b2f(resid[idx]);   // read-before-write, same thread
      Cout[idx] = f2b(fmaxf(val, 0.f));
    }
  }
}

// ---------------- attention core: scores + softmax + PV (VALU), per frame ----------------
__global__ __launch_bounds__(256) void attn_core(const bf16* __restrict__ Q,
                                                 const bf16* __restrict__ K,
                                                 const bf16* __restrict__ V,
                                                 const bf16* __restrict__ gbias,
                                                 float* __restrict__ attn_out,
                                                 bf16* __restrict__ ao_out){
  const int n = blockIdx.x;
  const int tid = threadIdx.x;
  __shared__ float sq[VJ][132];
  __shared__ float sk[VJ][132];
  __shared__ float sv[VJ][132];
  __shared__ float sc[NH*VJ*VJ];
  __shared__ float rmax[NH*VJ], rinv[NH*VJ];

  for (int idx = tid; idx < VJ*DM; idx += 256){
    int d = idx & (DM-1), v = idx >> 7;
    size_t g = ((size_t)n*VJ + v)*DM + d;
    sq[v][d] = b2f(Q[g]); sk[v][d] = b2f(K[g]); sv[v][d] = b2f(V[g]);
  }
  __syncthreads();
  const float scale = 0.17677669529663687f;   // 1/sqrt(32)
  for (int idx = tid; idx < NH*VJ*VJ; idx += 256){
    int j = idx % VJ, i2 = (idx/VJ) % VJ, h = idx/(VJ*VJ);
    float a = 0.f;
    #pragma unroll
    for (int dd = 0; dd < DH; ++dd)
      a = fmaf(sq[i2][h*DH + dd], sk[j][h*DH + dd], a);
    sc[idx] = a*scale + b2f(gbias[i2*VJ + j]);
  }
  __syncthreads();
  for (int r = tid; r < NH*VJ; r += 256){
    float m = -1e30f;
    for (int j = 0; j < VJ; ++j) m = fmaxf(m, sc[r*VJ + j]);
    float s = 0.f;
    for (int j = 0; j < VJ; ++j) s += __expf(sc[r*VJ + j] - m);
    rmax[r] = m; rinv[r] = 1.0f/s;
  }
  __syncthreads();
  for (int idx = tid; idx < NH*VJ*VJ; idx += 256){
    int r = idx / VJ;
    float e = __expf(sc[idx] - rmax[r]) * rinv[r];
    sc[idx] = e;
    attn_out[(size_t)n*(NH*VJ*VJ) + idx] = e;
  }
  __syncthreads();
  for (int idx = tid; idx < VJ*DM; idx += 256){
    int d = idx & (DM-1), v = idx >> 7, h = d >> 5;
    float acc = 0.f;
    #pragma unroll
    for (int j = 0; j < VJ; ++j)
      acc = fmaf(sc[(h*VJ + v)*VJ + j], sv[j][d], acc);
    ao_out[((size_t)n*VJ + v)*DM + d] = f2b(acc);
  }
}

// ---------------- agg: sa[n][w][c] = sum_u A[u][w] * x[n][u][c] ----------------
__global__ __launch_bounds__(256) void agg_kernel(const bf16* __restrict__ fin,
                                                  const bf16* __restrict__ An,
                                                  bf16* __restrict__ aout){
  const int n = blockIdx.x;
  const int tid = threadIdx.x;
  __shared__ float sx[VJ][132];
  __shared__ float sA[VJ*VJ];
  for (int i = tid; i < VJ*VJ; i += 256) sA[i] = b2f(An[i]);
  for (int idx = tid; idx < VJ*DM; idx += 256){
    int d = idx & (DM-1), v = idx >> 7;
    sx[v][d] = b2f(fin[((size_t)n*VJ + v)*DM + d]);
  }
  __syncthreads();
  for (int idx = tid; idx < VJ*DM; idx += 256){
    int c = idx & (DM-1), w = idx >> 7;
    float acc = 0.f;
    #pragma unroll
    for (int u = 0; u < VJ; ++u)
      acc = fmaf(sA[u*VJ + w], sx[u][c], acc);
    aout[((size_t)n*VJ + w)*DM + c] = f2b(acc);
  }
}

// ---------------- [B,T,V,D] bf16 -> [B,D,T,V] f32 transpose into d_out ----------------
__global__ __launch_bounds__(256) void transpose_out(const bf16* __restrict__ fin,
                                                     float* __restrict__ fout){
  const int bid = blockIdx.x;
  const int b   = bid >> 5;
  const int rem = bid & 31;
  const int t0  = (rem >> 2) * 32;
  const int d0  = (rem & 3) * 32;
  __shared__ bf16 tile[32][VJ][33];
  const int tid = threadIdx.x;
  for (int idx = tid; idx < 32*VJ*32; idx += 256){
    int dl = idx & 31;
    int v  = (idx >> 5) % VJ;
    int tl = idx / (32*VJ);
    tile[tl][v][dl] = fin[((size_t)(b*TLEN + t0 + tl)*VJ + v)*DM + d0 + dl];
  }
  __syncthreads();
  for (int idx = tid; idx < 32*VJ*32; idx += 256){
    int j  = idx % (32*VJ);
    int dl = idx / (32*VJ);
    int tl = j / VJ, v = j % VJ;
    fout[((size_t)(b*DM + d0 + dl)*TLEN + t0 + tl)*VJ + v] = b2f(tile[tl][v][dl]);
  }
}

extern "C" void kernel_launch(void* const* d_in, const int* in_sizes, int n_in,
                              void* d_out, int out_size, void* d_ws, size_t ws_size,
                              hipStream_t stream){
  const size_t featElems = (size_t)MTOK*DM;        // 44,040,192
  float* outf    = (float*)d_out;                  // [B,D,T,V] f32 (final)
  float* attnOut = outf + featElems;               // [N,H,V,V] f32 (final)
  // d_out's feature region doubles as scratch until the very last kernel:
  bf16* qbuf = (bf16*)d_out;                       // 88 MB  (dies after attn_core / reused as agg out)
  bf16* kbuf = qbuf + featElems;                   // 88 MB  (dies after attn_core / reused as gcn out)

  // ---- workspace layout (16B-aligned chunks) ----
  char* wp = (char*)d_ws;
  auto alloc = [&](size_t bytes)->char*{ char* p = wp; wp += (bytes + 15) & ~(size_t)15; return p; };
  int*  flag = (int*)alloc(16);
  ConvArgs ca; int total = 0;
  for (int i = 0; i < NIN; ++i){ ca.src[i] = d_in[i]; ca.off[i] = total; total += in_sizes[i]; }
  ca.off[NIN] = total;
  bf16* cin   = (bf16*)alloc((size_t)total*2);
  bf16* wqT   = (bf16*)alloc(DM*DM*2);
  bf16* wkT   = (bf16*)alloc(DM*DM*2);
  bf16* wvT   = (bf16*)alloc(DM*DM*2);
  bf16* woT   = (bf16*)alloc(DM*DM*2);
  bf16* twT1  = (bf16*)alloc(KT*DM*DM*2);
  bf16* twT2  = (bf16*)alloc(KT*DM*DM*2);
  bf16* featA = (bf16*)alloc(featElems*2);         // feat, later attention-output (ao)
  bf16* bufV  = (bf16*)alloc(featElems*2);         // V, later running feature map
  if ((size_t)(wp - (char*)d_ws) > ws_size) return;  // loud failure instead of corruption

  const bf16* x    = cin + ca.off[0];
  const bf16* cw   = cin + ca.off[1];
  const bf16* cb   = cin + ca.off[2];
  const bf16* je   = cin + ca.off[3];
  const bf16* gbias= cin + ca.off[4];
  const bf16* wq   = cin + ca.off[5];
  const bf16* bq   = cin + ca.off[6];
  const bf16* wk   = cin + ca.off[7];
  const bf16* bk   = cin + ca.off[8];
  const bf16* wv   = cin + ca.off[9];
  const bf16* bv   = cin + ca.off[10];
  const bf16* wo   = cin + ca.off[11];
  const bf16* bo   = cin + ca.off[12];
  const bf16* gw1  = cin + ca.off[13];
  const bf16* gb1  = cin + ca.off[14];
  const bf16* tw1  = cin + ca.off[15];
  const bf16* tb1  = cin + ca.off[16];
  const bf16* gw2  = cin + ca.off[17];
  const bf16* gb2  = cin + ca.off[18];
  const bf16* tw2  = cin + ca.off[19];
  const bf16* tb2  = cin + ca.off[20];
  const bf16* An   = cin + ca.off[21];

  const int GB = MTOK/64;                          // 5376 GEMM blocks
  hipMemsetAsync(flag, 0, sizeof(int), stream);
  detect_dtype<<<1, 256, 0, stream>>>(d_in[0], in_sizes[0], flag);
  convert_inputs<<<(total + 255)/256, 256, 0, stream>>>(ca, cin, flag, total);
  prep_weights<<<(KT*DM*DM + 255)/256, 256, 0, stream>>>(wq, wk, wv, wo, tw1, tw2,
                                                         wqT, wkT, wvT, woT, twT1, twT2);
  encode_kernel<<<(MTOK*16 + 255)/256, 256, 0, stream>>>(x, cw, cb, je, featA);
  gemm128<false><<<GB, 256, 0, stream>>>(featA, wqT, bq, qbuf);
  gemm128<false><<<GB, 256, 0, stream>>>(featA, wkT, bk, kbuf);
  gemm128<false><<<GB, 256, 0, stream>>>(featA, wvT, bv, bufV);
  attn_core<<<NFR, 256, 0, stream>>>(qbuf, kbuf, bufV, gbias, attnOut, featA); // ao -> featA
  gemm128<false><<<GB, 256, 0, stream>>>(featA, woT, bo, bufV);                // feat0 -> bufV
  // ST-GCN block 1
  agg_kernel<<<NFR, 256, 0, stream>>>(bufV, An, qbuf);
  gemm128<true><<<GB, 256, 0, stream>>>(qbuf, gw1, gb1, kbuf);                 // gw is already [d][c]=[n][k]
  tconv_gemm<<<GB, 256, 0, stream>>>(kbuf, twT1, tb1, bufV, bufV);
  // ST-GCN block 2
  agg_kernel<<<NFR, 256, 0, stream>>>(bufV, An, qbuf);
  gemm128<true><<<GB, 256, 0, stream>>>(qbuf, gw2, gb2, kbuf);
  tconv_gemm<<<GB, 256, 0, stream>>>(kbuf, twT2, tb2, bufV, bufV);
  transpose_out<<<BB*(TLEN/32)*(DM/32), 256, 0, stream>>>(bufV, outf);
}

// Round 5
// 1493.991 us; speedup vs baseline: 4.4296x; 2.2525x over previous
//
#include <hip/hip_runtime.h>
#include <hip/hip_bf16.h>

typedef __hip_bfloat16 bf16;
typedef __attribute__((ext_vector_type(8))) short short8v;
typedef __attribute__((ext_vector_type(4))) float float4v;

#define BB   64
#define CC   3
#define TLEN 256
#define VJ   21
#define DM   128
#define NH   4
#define DH   32
#define KT   9
#define NFR  (BB*TLEN)
#define MTOK (NFR*VJ)          // 344064 tokens = 2688 * 128
#define NIN  22

__device__ __forceinline__ float b2f(bf16 x){ return __bfloat162float(x); }
__device__ __forceinline__ bf16  f2b(float x){ return __float2bfloat16(x); }
__device__ __forceinline__ float hb2f(short s){ return __uint_as_float(((unsigned)(unsigned short)s) << 16); }

// ---------------- input dtype detection ----------------
__global__ void detect_dtype(const void* __restrict__ xin, int nus, int* __restrict__ flag){
  const unsigned short* u = (const unsigned short*)xin;
  int lim = nus < 65536 ? nus : 65536;
  int bad = 0;
  for (int k = threadIdx.x; k < lim; k += 256){
    float f = __uint_as_float(((unsigned)u[k]) << 16);
    if (!(fabsf(f) < 1e6f)) bad = 1;
  }
  if (bad) atomicOr(flag, 1);          // flag!=0 => inputs are float32
}

struct ConvArgs { const void* src[NIN]; int off[NIN+1]; };

__global__ void convert_inputs(ConvArgs a, bf16* __restrict__ dst,
                               const int* __restrict__ flag, int total){
  int i = blockIdx.x*256 + threadIdx.x;
  if (i >= total) return;
  bool isf32 = (*flag != 0);
  int k = 0;
  while (i >= a.off[k+1]) ++k;
  int j = i - a.off[k];
  float v;
  if (isf32) v = ((const float*)a.src[k])[j];
  else       v = __uint_as_float(((unsigned)((const unsigned short*)a.src[k])[j]) << 16);
  dst[i] = f2b(v);
}

// ---------------- weight prep ----------------
__global__ void prep_weights(const bf16* __restrict__ wq, const bf16* __restrict__ wk,
                             const bf16* __restrict__ wv, const bf16* __restrict__ wo,
                             const bf16* __restrict__ tw1, const bf16* __restrict__ tw2,
                             bf16* __restrict__ wqT, bf16* __restrict__ wkT,
                             bf16* __restrict__ wvT, bf16* __restrict__ woT,
                             bf16* __restrict__ twT1, bf16* __restrict__ twT2){
  int i = blockIdx.x*256 + threadIdx.x;
  if (i < DM*DM){
    int d = i >> 7, e = i & 127;            // wT[d][e] = w[e][d]
    wqT[i] = wq[e*DM + d];
    wkT[i] = wk[e*DM + d];
    wvT[i] = wv[e*DM + d];
    woT[i] = wo[e*DM + d];
  }
  if (i < KT*DM*DM){
    int c = i & 127; int d = (i >> 7) & 127; int tap = i >> 14;
    twT1[i] = tw1[(d*DM + c)*KT + tap];     // tw [d][c][kt][1]
    twT2[i] = tw2[(d*DM + c)*KT + tap];
  }
}

// ---------------- encode: feat[n][d] = coords@cw + cb + je ----------------
__global__ __launch_bounds__(256) void encode_kernel(const bf16* __restrict__ x,
                                                     const bf16* __restrict__ cw,
                                                     const bf16* __restrict__ cb,
                                                     const bf16* __restrict__ je,
                                                     bf16* __restrict__ feat){
  int idx = blockIdx.x*256 + threadIdx.x;        // one per (token, 8-wide d group)
  if (idx >= MTOK*16) return;
  int d0 = (idx & 15) * 8;
  int n  = idx >> 4;
  int v  = n % VJ; int t = (n / VJ) % TLEN; int b = n / (VJ*TLEN);
  float xs[CC];
  #pragma unroll
  for (int c = 0; c < CC; ++c)
    xs[c] = b2f(x[((size_t)(b*CC + c)*TLEN + t)*VJ + v]);
  short8v cwv[CC];
  #pragma unroll
  for (int c = 0; c < CC; ++c)
    cwv[c] = *reinterpret_cast<const short8v*>(cw + c*DM + d0);
  short8v cbv = *reinterpret_cast<const short8v*>(cb + d0);
  short8v jev = *reinterpret_cast<const short8v*>(je + v*DM + d0);
  #pragma unroll
  for (int e = 0; e < 8; ++e){
    float acc = hb2f(cbv[e]) + hb2f(jev[e]);
    #pragma unroll
    for (int c = 0; c < CC; ++c) acc = fmaf(xs[c], hb2f(cwv[c][e]), acc);
    feat[(size_t)n*DM + d0 + e] = f2b(acc);
  }
}

// ---------------- unified MFMA conv/GEMM kernel ----------------
// C[m][n] = sum_tap sum_k A[m + (tap-NTAPS/2)*VJ][k] * Bt[tap][n][k]  (+bias, +resid, relu)
// Block: 512 thr / 8 waves; BM=128 rows; wave = 64 rows x 32 cols.
// A staged in LDS (with halo), XOR-swizzled; B-fragments in registers per tap.
template<int NTAPS, bool RELU, bool RESID>
__global__ __launch_bounds__(512) void conv_gemm(const bf16* __restrict__ A,
                                                 const bf16* __restrict__ Bt,   // [NTAPS][128][128]
                                                 const bf16* __restrict__ bias,
                                                 const bf16* resid,             // may alias Cout
                                                 bf16* Cout){
  constexpr int HALO = (NTAPS/2)*VJ;          // 84 for 9-tap, 0 for 1x1
  constexpr int ROWS = 128 + 2*HALO;
  __shared__ short8v lds[ROWS*16];            // [row][16 chunks of 8 bf16], chunk ^= row&7
  const int tid = threadIdx.x;
  const int r0  = blockIdx.x*128;
  for (int i = tid; i < ROWS*16; i += 512){
    int row = i >> 4, c0 = i & 15;
    long tok = (long)r0 - HALO + row;
    if (tok < 0) tok = 0;
    if (tok > MTOK-1) tok = MTOK-1;           // clamped rows only feed invalid taps
    lds[row*16 + (c0 ^ (row & 7))] = *reinterpret_cast<const short8v*>(A + tok*DM + c0*8);
  }
  __syncthreads();
  const int lane = tid & 63;
  const int wid  = tid >> 6;
  const int rbase = (wid >> 2) * 64;          // row-half of the block
  const int nt0   = (wid & 3) * 2;            // col-tile pair
  const int l15 = lane & 15, l4 = lane >> 4;
  int trow[4];
  #pragma unroll
  for (int rt = 0; rt < 4; ++rt)
    trow[rt] = ((r0 + rbase + rt*16 + l15) / VJ) % TLEN;
  float4v acc[4][2];
  #pragma unroll
  for (int rt = 0; rt < 4; ++rt){ acc[rt][0] = (float4v){0,0,0,0}; acc[rt][1] = (float4v){0,0,0,0}; }

  for (int tap = 0; tap < NTAPS; ++tap){
    const bf16* Btap = Bt + (size_t)tap*DM*DM;
    short8v breg[2][4];
    #pragma unroll
    for (int ntl = 0; ntl < 2; ++ntl)
      #pragma unroll
      for (int ks = 0; ks < 4; ++ks)
        breg[ntl][ks] = *reinterpret_cast<const short8v*>(Btap + ((nt0+ntl)*16 + l15)*DM + ks*32 + l4*8);
    #pragma unroll
    for (int rt = 0; rt < 4; ++rt){
      bool valid = true;
      if (NTAPS > 1){
        int ts = trow[rt] + tap - NTAPS/2;
        valid = (ts >= 0) && (ts < TLEN);
      }
      const int ldsRow = rbase + rt*16 + l15 + HALO + (tap - NTAPS/2)*VJ;
      #pragma unroll
      for (int ks = 0; ks < 4; ++ks){
        short8v a = lds[ldsRow*16 + ((ks*4 + l4) ^ (ldsRow & 7))];
        if (NTAPS > 1 && !valid) a = (short8v){0,0,0,0,0,0,0,0};
        acc[rt][0] = __builtin_amdgcn_mfma_f32_16x16x32_bf16(a, breg[0][ks], acc[rt][0], 0,0,0);
        acc[rt][1] = __builtin_amdgcn_mfma_f32_16x16x32_bf16(a, breg[1][ks], acc[rt][1], 0,0,0);
      }
    }
  }
  #pragma unroll
  for (int rt = 0; rt < 4; ++rt){
    #pragma unroll
    for (int ntl = 0; ntl < 2; ++ntl){
      int col = (nt0+ntl)*16 + l15;
      float bv = b2f(bias[col]);
      #pragma unroll
      for (int j = 0; j < 4; ++j){
        size_t idx = (size_t)(r0 + rbase + rt*16 + l4*4 + j)*DM + col;
        float val = acc[rt][ntl][j] + bv;
        if (RESID) val += b2f(resid[idx]);     // read-before-write, same thread
        if (RELU) val = fmaxf(val, 0.f);
        Cout[idx] = f2b(val);
      }
    }
  }
}

// ---------------- attention core: scores + softmax + PV (VALU), per frame ----------------
__global__ __launch_bounds__(256) void attn_core(const bf16* __restrict__ Q,
                                                 const bf16* __restrict__ K,
                                                 const bf16* __restrict__ V,
                                                 const bf16* __restrict__ gbias,
                                                 float* __restrict__ attn_out,
                                                 bf16* __restrict__ ao_out){
  const int n = blockIdx.x;
  const int tid = threadIdx.x;
  __shared__ float sq[VJ][132];
  __shared__ float sk[VJ][132];
  __shared__ float sv[VJ][132];
  __shared__ float sc[NH*VJ*VJ];
  __shared__ float rmax[NH*VJ], rinv[NH*VJ];

  for (int idx = tid; idx < VJ*DM; idx += 256){
    int d = idx & (DM-1), v = idx >> 7;
    size_t g = ((size_t)n*VJ + v)*DM + d;
    sq[v][d] = b2f(Q[g]); sk[v][d] = b2f(K[g]); sv[v][d] = b2f(V[g]);
  }
  __syncthreads();
  const float scale = 0.17677669529663687f;   // 1/sqrt(32)
  for (int idx = tid; idx < NH*VJ*VJ; idx += 256){
    int j = idx % VJ, i2 = (idx/VJ) % VJ, h = idx/(VJ*VJ);
    float a = 0.f;
    #pragma unroll
    for (int dd = 0; dd < DH; ++dd)
      a = fmaf(sq[i2][h*DH + dd], sk[j][h*DH + dd], a);
    sc[idx] = a*scale + b2f(gbias[i2*VJ + j]);
  }
  __syncthreads();
  for (int r = tid; r < NH*VJ; r += 256){
    float m = -1e30f;
    for (int j = 0; j < VJ; ++j) m = fmaxf(m, sc[r*VJ + j]);
    float s = 0.f;
    for (int j = 0; j < VJ; ++j) s += __expf(sc[r*VJ + j] - m);
    rmax[r] = m; rinv[r] = 1.0f/s;
  }
  __syncthreads();
  for (int idx = tid; idx < NH*VJ*VJ; idx += 256){
    int r = idx / VJ;
    float e = __expf(sc[idx] - rmax[r]) * rinv[r];
    sc[idx] = e;
    attn_out[(size_t)n*(NH*VJ*VJ) + idx] = e;
  }
  __syncthreads();
  for (int idx = tid; idx < VJ*DM; idx += 256){
    int d = idx & (DM-1), v = idx >> 7, h = d >> 5;
    float acc = 0.f;
    #pragma unroll
    for (int j = 0; j < VJ; ++j)
      acc = fmaf(sc[(h*VJ + v)*VJ + j], sv[j][d], acc);
    ao_out[((size_t)n*VJ + v)*DM + d] = f2b(acc);
  }
}

// ---------------- agg: sa[n][w][c] = sum_u A[u][w] * x[n][u][c] ----------------
__global__ __launch_bounds__(256) void agg_kernel(const bf16* __restrict__ fin,
                                                  const bf16* __restrict__ An,
                                                  bf16* __restrict__ aout){
  const int n = blockIdx.x;
  const int tid = threadIdx.x;
  __shared__ float sx[VJ][132];
  __shared__ float sA[VJ*VJ];
  for (int i = tid; i < VJ*VJ; i += 256) sA[i] = b2f(An[i]);
  for (int idx = tid; idx < VJ*DM; idx += 256){
    int d = idx & (DM-1), v = idx >> 7;
    sx[v][d] = b2f(fin[((size_t)n*VJ + v)*DM + d]);
  }
  __syncthreads();
  for (int idx = tid; idx < VJ*DM; idx += 256){
    int c = idx & (DM-1), w = idx >> 7;
    float acc = 0.f;
    #pragma unroll
    for (int u = 0; u < VJ; ++u)
      acc = fmaf(sA[u*VJ + w], sx[u][c], acc);
    aout[((size_t)n*VJ + w)*DM + c] = f2b(acc);
  }
}

// ---------------- [B,T,V,D] bf16 -> [B,D,T,V] f32 transpose into d_out ----------------
__global__ __launch_bounds__(256) void transpose_out(const bf16* __restrict__ fin,
                                                     float* __restrict__ fout){
  const int bid = blockIdx.x;
  const int b   = bid >> 5;
  const int rem = bid & 31;
  const int t0  = (rem >> 2) * 32;
  const int d0  = (rem & 3) * 32;
  __shared__ bf16 tile[32][VJ][33];
  const int tid = threadIdx.x;
  for (int idx = tid; idx < 32*VJ*32; idx += 256){
    int dl = idx & 31;
    int v  = (idx >> 5) % VJ;
    int tl = idx / (32*VJ);
    tile[tl][v][dl] = fin[((size_t)(b*TLEN + t0 + tl)*VJ + v)*DM + d0 + dl];
  }
  __syncthreads();
  for (int idx = tid; idx < 32*VJ*32; idx += 256){
    int j  = idx % (32*VJ);
    int dl = idx / (32*VJ);
    int tl = j / VJ, v = j % VJ;
    fout[((size_t)(b*DM + d0 + dl)*TLEN + t0 + tl)*VJ + v] = b2f(tile[tl][v][dl]);
  }
}

extern "C" void kernel_launch(void* const* d_in, const int* in_sizes, int n_in,
                              void* d_out, int out_size, void* d_ws, size_t ws_size,
                              hipStream_t stream){
  const size_t featElems = (size_t)MTOK*DM;        // 44,040,192
  float* outf    = (float*)d_out;                  // [B,D,T,V] f32 (final)
  float* attnOut = outf + featElems;               // [N,H,V,V] f32 (final)
  // d_out's feature region doubles as scratch until the very last kernel:
  bf16* qbuf = (bf16*)d_out;                       // dies after attn_core / reused as agg out
  bf16* kbuf = qbuf + featElems;                   // dies after attn_core / reused as gcn out

  // ---- workspace layout (16B-aligned chunks) ----
  char* wp = (char*)d_ws;
  auto alloc = [&](size_t bytes)->char*{ char* p = wp; wp += (bytes + 15) & ~(size_t)15; return p; };
  int*  flag = (int*)alloc(16);
  ConvArgs ca; int total = 0;
  for (int i = 0; i < NIN; ++i){ ca.src[i] = d_in[i]; ca.off[i] = total; total += in_sizes[i]; }
  ca.off[NIN] = total;
  bf16* cin   = (bf16*)alloc((size_t)total*2);
  bf16* wqT   = (bf16*)alloc(DM*DM*2);
  bf16* wkT   = (bf16*)alloc(DM*DM*2);
  bf16* wvT   = (bf16*)alloc(DM*DM*2);
  bf16* woT   = (bf16*)alloc(DM*DM*2);
  bf16* twT1  = (bf16*)alloc(KT*DM*DM*2);
  bf16* twT2  = (bf16*)alloc(KT*DM*DM*2);
  bf16* featA = (bf16*)alloc(featElems*2);         // feat, later attention-output (ao)
  bf16* bufV  = (bf16*)alloc(featElems*2);         // V, later running feature map
  if ((size_t)(wp - (char*)d_ws) > ws_size) return;  // loud failure instead of corruption

  const bf16* x    = cin + ca.off[0];
  const bf16* cw   = cin + ca.off[1];
  const bf16* cb   = cin + ca.off[2];
  const bf16* je   = cin + ca.off[3];
  const bf16* gbias= cin + ca.off[4];
  const bf16* wq   = cin + ca.off[5];
  const bf16* bq   = cin + ca.off[6];
  const bf16* wk   = cin + ca.off[7];
  const bf16* bk   = cin + ca.off[8];
  const bf16* wv   = cin + ca.off[9];
  const bf16* bv   = cin + ca.off[10];
  const bf16* wo   = cin + ca.off[11];
  const bf16* bo   = cin + ca.off[12];
  const bf16* gw1  = cin + ca.off[13];
  const bf16* gb1  = cin + ca.off[14];
  const bf16* tw1  = cin + ca.off[15];
  const bf16* tb1  = cin + ca.off[16];
  const bf16* gw2  = cin + ca.off[17];
  const bf16* gb2  = cin + ca.off[18];
  const bf16* tw2  = cin + ca.off[19];
  const bf16* tb2  = cin + ca.off[20];
  const bf16* An   = cin + ca.off[21];

  const int GB = MTOK/128;                         // 2688 blocks
  hipMemsetAsync(flag, 0, sizeof(int), stream);
  detect_dtype<<<1, 256, 0, stream>>>(d_in[0], in_sizes[0], flag);
  convert_inputs<<<(total + 255)/256, 256, 0, stream>>>(ca, cin, flag, total);
  prep_weights<<<(KT*DM*DM + 255)/256, 256, 0, stream>>>(wq, wk, wv, wo, tw1, tw2,
                                                         wqT, wkT, wvT, woT, twT1, twT2);
  encode_kernel<<<(MTOK*16 + 255)/256, 256, 0, stream>>>(x, cw, cb, je, featA);
  conv_gemm<1,false,false><<<GB, 512, 0, stream>>>(featA, wqT, bq, nullptr, qbuf);
  conv_gemm<1,false,false><<<GB, 512, 0, stream>>>(featA, wkT, bk, nullptr, kbuf);
  conv_gemm<1,false,false><<<GB, 512, 0, stream>>>(featA, wvT, bv, nullptr, bufV);
  attn_core<<<NFR, 256, 0, stream>>>(qbuf, kbuf, bufV, gbias, attnOut, featA); // ao -> featA
  conv_gemm<1,false,false><<<GB, 512, 0, stream>>>(featA, woT, bo, nullptr, bufV);
  // ST-GCN block 1
  agg_kernel<<<NFR, 256, 0, stream>>>(bufV, An, qbuf);
  conv_gemm<1,true,false><<<GB, 512, 0, stream>>>(qbuf, gw1, gb1, nullptr, kbuf);  // gw already [n][k]
  conv_gemm<9,true,true><<<GB, 512, 0, stream>>>(kbuf, twT1, tb1, bufV, bufV);
  // ST-GCN block 2
  agg_kernel<<<NFR, 256, 0, stream>>>(bufV, An, qbuf);
  conv_gemm<1,true,false><<<GB, 512, 0, stream>>>(qbuf, gw2, gb2, nullptr, kbuf);
  conv_gemm<9,true,true><<<GB, 512, 0, stream>>>(kbuf, twT2, tb2, bufV, bufV);
  transpose_out<<<BB*(TLEN/32)*(DM/32), 256, 0, stream>>>(bufV, outf);
}

// Round 6
// 1344.120 us; speedup vs baseline: 4.9235x; 1.1115x over previous
//
#include <hip/hip_runtime.h>
#include <hip/hip_bf16.h>

typedef __hip_bfloat16 bf16;
typedef __attribute__((ext_vector_type(8))) short short8v;
typedef __attribute__((ext_vector_type(4))) float float4v;

#define BB   64
#define CC   3
#define TLEN 256
#define VJ   21
#define DM   128
#define NH   4
#define DH   32
#define KT   9
#define NFR  (BB*TLEN)
#define MTOK (NFR*VJ)          // 344064 tokens = 2688 * 128
#define NIN  22

__device__ __forceinline__ float b2f(bf16 x){ return __bfloat162float(x); }
__device__ __forceinline__ bf16  f2b(float x){ return __float2bfloat16(x); }
__device__ __forceinline__ float hb2f(short s){ return __uint_as_float(((unsigned)(unsigned short)s) << 16); }
__device__ __forceinline__ float lo16(unsigned u){ return __uint_as_float(u << 16); }
__device__ __forceinline__ float hi16(unsigned u){ return __uint_as_float(u & 0xffff0000u); }

// ---------------- input dtype detection ----------------
__global__ void detect_dtype(const void* __restrict__ xin, int nus, int* __restrict__ flag){
  const unsigned short* u = (const unsigned short*)xin;
  int lim = nus < 65536 ? nus : 65536;
  int bad = 0;
  for (int k = threadIdx.x; k < lim; k += 256){
    float f = __uint_as_float(((unsigned)u[k]) << 16);
    if (!(fabsf(f) < 1e6f)) bad = 1;
  }
  if (bad) atomicOr(flag, 1);          // flag!=0 => inputs are float32
}

struct ConvArgs { const void* src[NIN]; int off[NIN+1]; };

__global__ void convert_inputs(ConvArgs a, bf16* __restrict__ dst,
                               const int* __restrict__ flag, int total){
  int i = blockIdx.x*256 + threadIdx.x;
  if (i >= total) return;
  bool isf32 = (*flag != 0);
  int k = 0;
  while (i >= a.off[k+1]) ++k;
  int j = i - a.off[k];
  float v;
  if (isf32) v = ((const float*)a.src[k])[j];
  else       v = __uint_as_float(((unsigned)((const unsigned short*)a.src[k])[j]) << 16);
  dst[i] = f2b(v);
}

// ---------------- weight prep ----------------
__global__ void prep_weights(const bf16* __restrict__ wq, const bf16* __restrict__ wk,
                             const bf16* __restrict__ wv, const bf16* __restrict__ wo,
                             const bf16* __restrict__ tw1, const bf16* __restrict__ tw2,
                             bf16* __restrict__ wqT, bf16* __restrict__ wkT,
                             bf16* __restrict__ wvT, bf16* __restrict__ woT,
                             bf16* __restrict__ twT1, bf16* __restrict__ twT2){
  int i = blockIdx.x*256 + threadIdx.x;
  if (i < DM*DM){
    int d = i >> 7, e = i & 127;            // wT[d][e] = w[e][d]
    wqT[i] = wq[e*DM + d];
    wkT[i] = wk[e*DM + d];
    wvT[i] = wv[e*DM + d];
    woT[i] = wo[e*DM + d];
  }
  if (i < KT*DM*DM){
    int c = i & 127; int d = (i >> 7) & 127; int tap = i >> 14;
    twT1[i] = tw1[(d*DM + c)*KT + tap];     // tw [d][c][kt][1]
    twT2[i] = tw2[(d*DM + c)*KT + tap];
  }
}

// ---------------- encode: feat[n][d] = coords@cw + cb + je ----------------
__global__ __launch_bounds__(256) void encode_kernel(const bf16* __restrict__ x,
                                                     const bf16* __restrict__ cw,
                                                     const bf16* __restrict__ cb,
                                                     const bf16* __restrict__ je,
                                                     bf16* __restrict__ feat){
  int idx = blockIdx.x*256 + threadIdx.x;        // one per (token, 8-wide d group)
  if (idx >= MTOK*16) return;
  int d0 = (idx & 15) * 8;
  int n  = idx >> 4;
  int v  = n % VJ; int t = (n / VJ) % TLEN; int b = n / (VJ*TLEN);
  float xs[CC];
  #pragma unroll
  for (int c = 0; c < CC; ++c)
    xs[c] = b2f(x[((size_t)(b*CC + c)*TLEN + t)*VJ + v]);
  short8v cwv[CC];
  #pragma unroll
  for (int c = 0; c < CC; ++c)
    cwv[c] = *reinterpret_cast<const short8v*>(cw + c*DM + d0);
  short8v cbv = *reinterpret_cast<const short8v*>(cb + d0);
  short8v jev = *reinterpret_cast<const short8v*>(je + v*DM + d0);
  short8v out;
  #pragma unroll
  for (int e = 0; e < 8; ++e){
    float acc = hb2f(cbv[e]) + hb2f(jev[e]);
    #pragma unroll
    for (int c = 0; c < CC; ++c) acc = fmaf(xs[c], hb2f(cwv[c][e]), acc);
    bf16 h = f2b(acc);
    out[e] = *reinterpret_cast<short*>(&h);
  }
  *reinterpret_cast<short8v*>(feat + (size_t)n*DM + d0*1) = out;
}

// ---------------- fused Q/K/V GEMM: stage A once, 3 weight sets ----------------
__global__ __launch_bounds__(512) void qkv_gemm(const bf16* __restrict__ A,
                                                const bf16* __restrict__ BtQ,
                                                const bf16* __restrict__ BtK,
                                                const bf16* __restrict__ BtV,
                                                const bf16* __restrict__ bq,
                                                const bf16* __restrict__ bk,
                                                const bf16* __restrict__ bv,
                                                bf16* __restrict__ Oq,
                                                bf16* __restrict__ Ok,
                                                bf16* __restrict__ Ov){
  __shared__ short8v lds[128*16];
  const int tid = threadIdx.x;
  const int r0  = blockIdx.x*128;
  for (int i = tid; i < 128*16; i += 512){
    int row = i >> 4, c0 = i & 15;
    lds[row*16 + (c0 ^ (row & 7))] = *reinterpret_cast<const short8v*>(A + ((size_t)r0 + row)*DM + c0*8);
  }
  __syncthreads();
  const int lane = tid & 63;
  const int wid  = tid >> 6;
  const int rbase = (wid >> 2) * 64;
  const int nt0   = (wid & 3) * 2;
  const int l15 = lane & 15, l4 = lane >> 4;
  #pragma unroll
  for (int w = 0; w < 3; ++w){
    const bf16* Bt  = (w==0) ? BtQ : (w==1) ? BtK : BtV;
    const bf16* bia = (w==0) ? bq  : (w==1) ? bk  : bv;
    bf16*       Out = (w==0) ? Oq  : (w==1) ? Ok  : Ov;
    short8v breg[2][4];
    #pragma unroll
    for (int ntl = 0; ntl < 2; ++ntl)
      #pragma unroll
      for (int ks = 0; ks < 4; ++ks)
        breg[ntl][ks] = *reinterpret_cast<const short8v*>(Bt + ((nt0+ntl)*16 + l15)*DM + ks*32 + l4*8);
    float4v acc[4][2];
    #pragma unroll
    for (int rt = 0; rt < 4; ++rt){ acc[rt][0] = (float4v){0,0,0,0}; acc[rt][1] = (float4v){0,0,0,0}; }
    #pragma unroll
    for (int rt = 0; rt < 4; ++rt){
      const int ldsRow = rbase + rt*16 + l15;
      #pragma unroll
      for (int ks = 0; ks < 4; ++ks){
        short8v a = lds[ldsRow*16 + ((ks*4 + l4) ^ (ldsRow & 7))];
        acc[rt][0] = __builtin_amdgcn_mfma_f32_16x16x32_bf16(a, breg[0][ks], acc[rt][0], 0,0,0);
        acc[rt][1] = __builtin_amdgcn_mfma_f32_16x16x32_bf16(a, breg[1][ks], acc[rt][1], 0,0,0);
      }
    }
    #pragma unroll
    for (int rt = 0; rt < 4; ++rt)
      #pragma unroll
      for (int ntl = 0; ntl < 2; ++ntl){
        int col = (nt0+ntl)*16 + l15;
        float bvv = b2f(bia[col]);
        #pragma unroll
        for (int j = 0; j < 4; ++j)
          Out[(size_t)(r0 + rbase + rt*16 + l4*4 + j)*DM + col] = f2b(acc[rt][ntl][j] + bvv);
      }
  }
}

// ---------------- unified MFMA conv/GEMM kernel ----------------
template<int NTAPS, bool RELU, bool RESID>
__global__ __launch_bounds__(512) void conv_gemm(const bf16* __restrict__ A,
                                                 const bf16* __restrict__ Bt,   // [NTAPS][128][128]
                                                 const bf16* __restrict__ bias,
                                                 const bf16* resid,             // may alias Cout
                                                 bf16* Cout){
  constexpr int HALO = (NTAPS/2)*VJ;          // 84 for 9-tap, 0 for 1x1
  constexpr int ROWS = 128 + 2*HALO;
  __shared__ short8v lds[ROWS*16];            // [row][16 chunks of 8 bf16], chunk ^= row&7
  const int tid = threadIdx.x;
  const int r0  = blockIdx.x*128;
  for (int i = tid; i < ROWS*16; i += 512){
    int row = i >> 4, c0 = i & 15;
    long tok = (long)r0 - HALO + row;
    if (tok < 0) tok = 0;
    if (tok > MTOK-1) tok = MTOK-1;           // clamped rows only feed invalid taps
    lds[row*16 + (c0 ^ (row & 7))] = *reinterpret_cast<const short8v*>(A + tok*DM + c0*8);
  }
  __syncthreads();
  const int lane = tid & 63;
  const int wid  = tid >> 6;
  const int rbase = (wid >> 2) * 64;          // row-half of the block
  const int nt0   = (wid & 3) * 2;            // col-tile pair
  const int l15 = lane & 15, l4 = lane >> 4;
  int trow[4];
  #pragma unroll
  for (int rt = 0; rt < 4; ++rt)
    trow[rt] = ((r0 + rbase + rt*16 + l15) / VJ) % TLEN;
  float4v acc[4][2];
  #pragma unroll
  for (int rt = 0; rt < 4; ++rt){ acc[rt][0] = (float4v){0,0,0,0}; acc[rt][1] = (float4v){0,0,0,0}; }

  for (int tap = 0; tap < NTAPS; ++tap){
    const bf16* Btap = Bt + (size_t)tap*DM*DM;
    short8v breg[2][4];
    #pragma unroll
    for (int ntl = 0; ntl < 2; ++ntl)
      #pragma unroll
      for (int ks = 0; ks < 4; ++ks)
        breg[ntl][ks] = *reinterpret_cast<const short8v*>(Btap + ((nt0+ntl)*16 + l15)*DM + ks*32 + l4*8);
    #pragma unroll
    for (int rt = 0; rt < 4; ++rt){
      bool valid = true;
      if (NTAPS > 1){
        int ts = trow[rt] + tap - NTAPS/2;
        valid = (ts >= 0) && (ts < TLEN);
      }
      const int ldsRow = rbase + rt*16 + l15 + HALO + (tap - NTAPS/2)*VJ;
      #pragma unroll
      for (int ks = 0; ks < 4; ++ks){
        short8v a = lds[ldsRow*16 + ((ks*4 + l4) ^ (ldsRow & 7))];
        if (NTAPS > 1 && !valid) a = (short8v){0,0,0,0,0,0,0,0};
        acc[rt][0] = __builtin_amdgcn_mfma_f32_16x16x32_bf16(a, breg[0][ks], acc[rt][0], 0,0,0);
        acc[rt][1] = __builtin_amdgcn_mfma_f32_16x16x32_bf16(a, breg[1][ks], acc[rt][1], 0,0,0);
      }
    }
  }
  #pragma unroll
  for (int rt = 0; rt < 4; ++rt){
    #pragma unroll
    for (int ntl = 0; ntl < 2; ++ntl){
      int col = (nt0+ntl)*16 + l15;
      float bv = b2f(bias[col]);
      #pragma unroll
      for (int j = 0; j < 4; ++j){
        size_t idx = (size_t)(r0 + rbase + rt*16 + l4*4 + j)*DM + col;
        float val = acc[rt][ntl][j] + bv;
        if (RESID) val += b2f(resid[idx]);     // read-before-write, same thread
        if (RELU) val = fmaxf(val, 0.f);
        Cout[idx] = f2b(val);
      }
    }
  }
}

// ---------------- attention core v2: bf16 LDS, vectorized, high occupancy ----------------
__global__ __launch_bounds__(256) void attn_core(const bf16* __restrict__ Q,
                                                 const bf16* __restrict__ K,
                                                 const bf16* __restrict__ V,
                                                 const bf16* __restrict__ gbias,
                                                 float* __restrict__ attn_out,
                                                 bf16* __restrict__ ao_out){
  const int n = blockIdx.x;
  const int tid = threadIdx.x;
  __shared__ bf16 skv[3][VJ][136];     // q,k,v rows; stride 136 (16B-aligned chunks)
  __shared__ float sc[NH*VJ*VJ];
  __shared__ float rmax[NH*VJ], rinv[NH*VJ];
  __shared__ bf16 sgb[VJ*VJ];

  for (int i = tid; i < VJ*VJ; i += 256) sgb[i] = gbias[i];
  for (int i = tid; i < 3*VJ*16; i += 256){
    int c0 = i & 15; int v = (i >> 4) % VJ; int w = i / (16*VJ);
    const bf16* src = (w==0 ? Q : (w==1 ? K : V)) + ((size_t)n*VJ + v)*DM + c0*8;
    *reinterpret_cast<short8v*>(&skv[w][v][c0*8]) = *reinterpret_cast<const short8v*>(src);
  }
  __syncthreads();
  const float scale = 0.17677669529663687f;   // 1/sqrt(32)
  for (int idx = tid; idx < NH*VJ*VJ; idx += 256){
    int j = idx % VJ, i2 = (idx/VJ) % VJ, h = idx/(VJ*VJ);
    const unsigned* qr = reinterpret_cast<const unsigned*>(&skv[0][i2][h*DH]);
    const unsigned* kr = reinterpret_cast<const unsigned*>(&skv[1][j][h*DH]);
    float a = 0.f;
    #pragma unroll
    for (int p = 0; p < DH/2; ++p){
      unsigned qa = qr[p], ka = kr[p];
      a = fmaf(lo16(qa), lo16(ka), a);
      a = fmaf(hi16(qa), hi16(ka), a);
    }
    sc[idx] = a*scale + b2f(sgb[i2*VJ + j]);
  }
  __syncthreads();
  for (int r = tid; r < NH*VJ; r += 256){
    float m = -1e30f;
    for (int j = 0; j < VJ; ++j) m = fmaxf(m, sc[r*VJ + j]);
    float s = 0.f;
    for (int j = 0; j < VJ; ++j) s += __expf(sc[r*VJ + j] - m);
    rmax[r] = m; rinv[r] = 1.0f/s;
  }
  __syncthreads();
  for (int idx = tid; idx < NH*VJ*VJ; idx += 256){
    int r = idx / VJ;
    float e = __expf(sc[idx] - rmax[r]) * rinv[r];
    sc[idx] = e;
    attn_out[(size_t)n*(NH*VJ*VJ) + idx] = e;
  }
  __syncthreads();
  // PV: thread owns 2 d's; packed bf16 reads of V, packed write of ao
  unsigned* aoU = reinterpret_cast<unsigned*>(ao_out);
  for (int i = tid; i < VJ*(DM/2); i += 256){
    int q2 = i & 63; int v = i >> 6;
    int d0 = q2*2; int h = d0 >> 5;
    const float* pr = &sc[(h*VJ + v)*VJ];
    float a0 = 0.f, a1 = 0.f;
    #pragma unroll
    for (int j = 0; j < VJ; ++j){
      unsigned va = *reinterpret_cast<const unsigned*>(&skv[2][j][d0]);
      float p = pr[j];
      a0 = fmaf(p, lo16(va), a0);
      a1 = fmaf(p, hi16(va), a1);
    }
    bf16 b0 = f2b(a0), b1 = f2b(a1);
    unsigned u0 = *reinterpret_cast<unsigned short*>(&b0);
    unsigned u1 = *reinterpret_cast<unsigned short*>(&b1);
    aoU[((size_t)n*VJ + v)*(DM/2) + q2] = u0 | (u1 << 16);
  }
}

// ---------------- agg v2: vectorized; sa[n][w][c] = sum_u A[u][w] * x[n][u][c] ----------------
__global__ __launch_bounds__(256) void agg_kernel(const bf16* __restrict__ fin,
                                                  const bf16* __restrict__ An,
                                                  bf16* __restrict__ aout){
  const int n = blockIdx.x;
  const int tid = threadIdx.x;
  __shared__ bf16 sx[VJ][136];
  __shared__ float sA[VJ*VJ];
  for (int i = tid; i < VJ*VJ; i += 256) sA[i] = b2f(An[i]);
  for (int i = tid; i < VJ*16; i += 256){
    int c0 = i & 15, v = i >> 4;
    *reinterpret_cast<short8v*>(&sx[v][c0*8]) =
      *reinterpret_cast<const short8v*>(fin + ((size_t)n*VJ + v)*DM + c0*8);
  }
  __syncthreads();
  for (int i = tid; i < VJ*16; i += 256){
    int c0 = i & 15, w = i >> 4;
    float acc[8] = {0,0,0,0,0,0,0,0};
    #pragma unroll
    for (int u = 0; u < VJ; ++u){
      float a = sA[u*VJ + w];
      short8v xv = *reinterpret_cast<const short8v*>(&sx[u][c0*8]);
      #pragma unroll
      for (int e = 0; e < 8; ++e) acc[e] = fmaf(a, hb2f(xv[e]), acc[e]);
    }
    short8v out;
    #pragma unroll
    for (int e = 0; e < 8; ++e){ bf16 h = f2b(acc[e]); out[e] = *reinterpret_cast<short*>(&h); }
    *reinterpret_cast<short8v*>(aout + ((size_t)n*VJ + w)*DM + c0*8) = out;
  }
}

// ---------------- [B,T,V,D] bf16 -> [B,D,T,V] f32 transpose into d_out ----------------
__global__ __launch_bounds__(256) void transpose_out(const bf16* __restrict__ fin,
                                                     float* __restrict__ fout){
  const int bid = blockIdx.x;
  const int b   = bid >> 5;
  const int rem = bid & 31;
  const int t0  = (rem >> 2) * 32;
  const int d0  = (rem & 3) * 32;
  __shared__ bf16 tile[32][VJ][33];
  const int tid = threadIdx.x;
  for (int idx = tid; idx < 32*VJ*32; idx += 256){
    int dl = idx & 31;
    int v  = (idx >> 5) % VJ;
    int tl = idx / (32*VJ);
    tile[tl][v][dl] = fin[((size_t)(b*TLEN + t0 + tl)*VJ + v)*DM + d0 + dl];
  }
  __syncthreads();
  for (int idx = tid; idx < 32*VJ*32; idx += 256){
    int j  = idx % (32*VJ);
    int dl = idx / (32*VJ);
    int tl = j / VJ, v = j % VJ;
    fout[((size_t)(b*DM + d0 + dl)*TLEN + t0 + tl)*VJ + v] = b2f(tile[tl][v][dl]);
  }
}

extern "C" void kernel_launch(void* const* d_in, const int* in_sizes, int n_in,
                              void* d_out, int out_size, void* d_ws, size_t ws_size,
                              hipStream_t stream){
  const size_t featElems = (size_t)MTOK*DM;        // 44,040,192
  float* outf    = (float*)d_out;                  // [B,D,T,V] f32 (final)
  float* attnOut = outf + featElems;               // [N,H,V,V] f32 (final)
  // d_out's feature region doubles as scratch until the very last kernel:
  bf16* qbuf = (bf16*)d_out;                       // dies after attn_core / reused as agg out
  bf16* kbuf = qbuf + featElems;                   // dies after attn_core / reused as gcn out

  // ---- workspace layout (16B-aligned chunks) ----
  char* wp = (char*)d_ws;
  auto alloc = [&](size_t bytes)->char*{ char* p = wp; wp += (bytes + 15) & ~(size_t)15; return p; };
  int*  flag = (int*)alloc(16);
  ConvArgs ca; int total = 0;
  for (int i = 0; i < NIN; ++i){ ca.src[i] = d_in[i]; ca.off[i] = total; total += in_sizes[i]; }
  ca.off[NIN] = total;
  bf16* cin   = (bf16*)alloc((size_t)total*2);
  bf16* wqT   = (bf16*)alloc(DM*DM*2);
  bf16* wkT   = (bf16*)alloc(DM*DM*2);
  bf16* wvT   = (bf16*)alloc(DM*DM*2);
  bf16* woT   = (bf16*)alloc(DM*DM*2);
  bf16* twT1  = (bf16*)alloc(KT*DM*DM*2);
  bf16* twT2  = (bf16*)alloc(KT*DM*DM*2);
  bf16* featA = (bf16*)alloc(featElems*2);         // feat, later attention-output (ao)
  bf16* bufV  = (bf16*)alloc(featElems*2);         // V, later running feature map
  if ((size_t)(wp - (char*)d_ws) > ws_size) return;  // loud failure instead of corruption

  const bf16* x    = cin + ca.off[0];
  const bf16* cw   = cin + ca.off[1];
  const bf16* cb   = cin + ca.off[2];
  const bf16* je   = cin + ca.off[3];
  const bf16* gbias= cin + ca.off[4];
  const bf16* wq   = cin + ca.off[5];
  const bf16* bq   = cin + ca.off[6];
  const bf16* wk   = cin + ca.off[7];
  const bf16* bk   = cin + ca.off[8];
  const bf16* wv   = cin + ca.off[9];
  const bf16* bv   = cin + ca.off[10];
  const bf16* wo   = cin + ca.off[11];
  const bf16* bo   = cin + ca.off[12];
  const bf16* gw1  = cin + ca.off[13];
  const bf16* gb1  = cin + ca.off[14];
  const bf16* tw1  = cin + ca.off[15];
  const bf16* tb1  = cin + ca.off[16];
  const bf16* gw2  = cin + ca.off[17];
  const bf16* gb2  = cin + ca.off[18];
  const bf16* tw2  = cin + ca.off[19];
  const bf16* tb2  = cin + ca.off[20];
  const bf16* An   = cin + ca.off[21];

  const int GB = MTOK/128;                         // 2688 blocks
  hipMemsetAsync(flag, 0, sizeof(int), stream);
  detect_dtype<<<1, 256, 0, stream>>>(d_in[0], in_sizes[0], flag);
  convert_inputs<<<(total + 255)/256, 256, 0, stream>>>(ca, cin, flag, total);
  prep_weights<<<(KT*DM*DM + 255)/256, 256, 0, stream>>>(wq, wk, wv, wo, tw1, tw2,
                                                         wqT, wkT, wvT, woT, twT1, twT2);
  encode_kernel<<<(MTOK*16 + 255)/256, 256, 0, stream>>>(x, cw, cb, je, featA);
  qkv_gemm<<<GB, 512, 0, stream>>>(featA, wqT, wkT, wvT, bq, bk, bv, qbuf, kbuf, bufV);
  attn_core<<<NFR, 256, 0, stream>>>(qbuf, kbuf, bufV, gbias, attnOut, featA); // ao -> featA
  conv_gemm<1,false,false><<<GB, 512, 0, stream>>>(featA, woT, bo, nullptr, bufV);
  // ST-GCN block 1
  agg_kernel<<<NFR, 256, 0, stream>>>(bufV, An, qbuf);
  conv_gemm<1,true,false><<<GB, 512, 0, stream>>>(qbuf, gw1, gb1, nullptr, kbuf);  // gw already [n][k]
  conv_gemm<9,true,true><<<GB, 512, 0, stream>>>(kbuf, twT1, tb1, bufV, bufV);
  // ST-GCN block 2
  agg_kernel<<<NFR, 256, 0, stream>>>(bufV, An, qbuf);
  conv_gemm<1,true,false><<<GB, 512, 0, stream>>>(qbuf, gw2, gb2, nullptr, kbuf);
  conv_gemm<9,true,true><<<GB, 512, 0, stream>>>(kbuf, twT2, tb2, bufV, bufV);
  transpose_out<<<BB*(TLEN/32)*(DM/32), 256, 0, stream>>>(bufV, outf);
}